// Round 10
// baseline (518.322 us; speedup 1.0000x reference)
//
#include <hip/hip_runtime.h>
#include <limits.h>

#define BLOCK 256
#define CHUNK 2
#define SPAN  64
#define PERSIST_BLOCKS 1792   // 7 blocks/CU x 256 CUs; __launch_bounds__(256,7)

typedef float v2f __attribute__((ext_vector_type(2)));

__device__ __forceinline__ v2f pk_fma(v2f a, v2f b, v2f c) {
    return __builtin_elementwise_fma(a, b, c);
}
__device__ __forceinline__ float leaky_(float x){ return x >= 0.f ? x : 0.01f*x; }

// Packed weight-table layout (floats), built once by prep, block-copied to LDS:
#define L_W2AI   0      // 16*20: k-pair interleaved L1 weights {w2a[2kp][j],w2a[2kp+1][j]} j<9, pad 2
#define L_W2BT   320    // 32*16: w2bT[k][m] = w2b[m*32+k]
#define L_W2CT   832    // 16*8 : w2cT[m][p] = w2c[p*16+m], pad p<8
#define L_B2B    960    // 16
#define L_B2C    976    // 8 (pad)
#define L_W013   984    // 3 mats x 3 rows x4: (w,w,w,b) for w0,w1,w1n
#define WTAB_SZ  1024
#define L_ACC    1024   // SPAN*6 block-local segment accumulator
#define L_TOT    (1024 + SPAN*6)

// ---------------- Kernel A: per-structure precompute + weight packing ------
__global__ void prep_kernel(const float* __restrict__ cell,
                            const float* __restrict__ w2a,
                            const float* __restrict__ b2a,
                            const float* __restrict__ w2b,
                            const float* __restrict__ w2c,
                            const float* __restrict__ w0, const float* __restrict__ b0,
                            const float* __restrict__ w1, const float* __restrict__ b1,
                            const float* __restrict__ w1n, const float* __restrict__ b1n,
                            const float* __restrict__ b2b, const float* __restrict__ b2c,
                            float* __restrict__ ci_out,
                            float* __restrict__ cc_out,
                            float* __restrict__ wtab,
                            float* __restrict__ out_zero,
                            int S)
{
    int gid = blockIdx.x * blockDim.x + threadIdx.x;

    if (gid < S * 6) out_zero[gid] = 0.f;

    // ---- wtab packing ----
    if (gid < 320) {
        int kp = gid / 20, idx = gid % 20;
        int j = idx >> 1, h = idx & 1;
        wtab[L_W2AI + gid] = (idx < 18) ? w2a[(2*kp + h)*90 + j] : 0.f;
    } else if (gid < 832) {
        int t = gid - 320; int k = t >> 4, m = t & 15;
        wtab[gid] = w2b[m*32 + k];
    } else if (gid < 960) {
        int t = gid - 832; int m = t >> 3, p = t & 7;
        wtab[gid] = (p < 6) ? w2c[p*16 + m] : 0.f;
    } else if (gid < 976) {
        wtab[gid] = b2b[gid - 960];
    } else if (gid < 984) {
        int t = gid - 976; wtab[gid] = (t < 6) ? b2c[t] : 0.f;
    } else if (gid < 1024) {
        int t = gid - 984;
        if (t < 36) {
            int mat = t / 12, rr = t % 12, r = rr >> 2, c = rr & 3;
            const float* W = (mat == 0) ? w0 : (mat == 1) ? w1 : w1n;
            const float* B = (mat == 0) ? b0 : (mat == 1) ? b1 : b1n;
            wtab[gid] = (c < 3) ? W[r*3 + c] : B[r];
        } else wtab[gid] = 0.f;
    }

    int s = gid >> 5;
    if (s >= S) return;
    int k = gid & 31;

    float cr[9];
    #pragma unroll
    for (int j = 0; j < 9; j++) cr[j] = cell[s*9 + j];

    if (k == 0) {
        float a=cr[0],b=cr[1],c=cr[2],d=cr[3],e=cr[4],f=cr[5],g=cr[6],h=cr[7],i=cr[8];
        float A = e*i - f*h;
        float B = f*g - d*i;
        float C = d*h - e*g;
        float det = a*A + b*B + c*C;
        float r = 1.0f / det;
        float* o = ci_out + s*12;
        o[0] = A*r;         o[1] = (c*h - b*i)*r; o[2] = (b*f - c*e)*r;
        o[3] = B*r;         o[4] = (a*i - c*g)*r; o[5] = (c*d - a*f)*r;
        o[6] = C*r;         o[7] = (b*g - a*h)*r; o[8] = (a*e - b*d)*r;
        o[9] = 0.f; o[10] = 0.f; o[11] = 0.f;
    }

    float acc = b2a[k];
    const float* wr = w2a + k*90 + 9;
    #pragma unroll
    for (int j1 = 0; j1 < 9; j1++) {
        float c1 = cr[j1];
        #pragma unroll
        for (int j2 = 0; j2 < 9; j2++)
            acc = fmaf(c1 * cr[j2], wr[j1*9 + j2], acc);
    }
    cc_out[s*32 + k] = acc;
}

// ---------------- Kernel B: persistent per-atom MLP + segment sum ----------
__global__ __launch_bounds__(BLOCK, 7)
void main_kernel(const float* __restrict__ atom_prop,
                 const float* __restrict__ pos,
                 const int*   __restrict__ batch,
                 const float* __restrict__ ci_ws,
                 const float* __restrict__ cc_ws,
                 const float* __restrict__ wtab,
                 float* __restrict__ out,
                 int N, int S, int ntiles)
{
    __shared__ float lds[L_TOT];
    int tid = threadIdx.x;

    // one coalesced float4 per thread loads the whole weight table
    ((float4*)lds)[tid] = ((const float4*)wtab)[tid];

    for (int tile = blockIdx.x; tile < ntiles; tile += gridDim.x) {
        long long blk_base = (long long)tile * (BLOCK * CHUNK);
        int s0 = batch[(blk_base < N) ? blk_base : (N - 1)];

        __syncthreads();   // previous flush done (and first-iter: wtab visible)
        for (int t = tid; t < SPAN*6; t += BLOCK) lds[L_ACC + t] = 0.f;
        __syncthreads();

        long long base = blk_base + (long long)tid * CHUNK;
        bool any = (base < N);

        int   sv[CHUNK];
        float PX[CHUNK], PY[CHUNK], PZ[CHUNK];
        float AX[CHUNK], AY[CHUNK], AZ[CHUNK];

        if (any && base + CHUNK <= N) {
            int2 bb = *(const int2*)(batch + base);
            sv[0] = bb.x; sv[1] = bb.y;
            const float2* pp = (const float2*)(pos + 3*base);
            float2 p0 = pp[0], p1 = pp[1], p2 = pp[2];
            PX[0]=p0.x; PY[0]=p0.y; PZ[0]=p1.x;
            PX[1]=p1.y; PY[1]=p2.x; PZ[1]=p2.y;
            const float2* ap = (const float2*)(atom_prop + 3*base);
            float2 a0 = ap[0], a1 = ap[1], a2 = ap[2];
            AX[0]=a0.x; AY[0]=a0.y; AZ[0]=a1.x;
            AX[1]=a1.y; AY[1]=a2.x; AZ[1]=a2.y;
        } else {
            #pragma unroll
            for (int t = 0; t < CHUNK; t++) {
                long long i = base + t;
                bool ok = any && (i < N);
                sv[t] = ok ? batch[i] : -1;
                PX[t] = ok ? pos[3*i]   : 0.f;
                PY[t] = ok ? pos[3*i+1] : 0.f;
                PZ[t] = ok ? pos[3*i+2] : 0.f;
                AX[t] = ok ? atom_prop[3*i]   : 0.f;
                AY[t] = ok ? atom_prop[3*i+1] : 0.f;
                AZ[t] = ok ? atom_prop[3*i+2] : 0.f;
            }
        }

        // issue cc prefetch early (independent of phase 1)
        const float* ccp[CHUNK];
        #pragma unroll
        for (int t = 0; t < CHUNK; t++) {
            int s = sv[t] < 0 ? 0 : sv[t];
            ccp[t] = cc_ws + (size_t)s*32;
        }
        float4 c4n[CHUNK];
        #pragma unroll
        for (int t = 0; t < CHUNK; t++) c4n[t] = *(const float4*)(ccp[t]);

        // ---- phase 1: h per atom (splat pairs) ----
        v2f h2[CHUNK][9];
        {
            const float4* q0 = (const float4*)(lds + L_W013);
            const float4* q1 = (const float4*)(lds + L_W013 + 12);
            const float4* q2 = (const float4*)(lds + L_W013 + 24);
            int   cur_s = -1;
            float ci[9];
            #pragma unroll
            for (int t = 0; t < CHUNK; t++) {
                int s = sv[t];
                if (s < 0) {
                    #pragma unroll
                    for (int j = 0; j < 9; j++) h2[t][j] = 0.f;
                    continue;
                }
                if (s != cur_s) {
                    cur_s = s;
                    const float4* cip = (const float4*)(ci_ws + (size_t)s*12);
                    float4 c0 = cip[0], c1 = cip[1], c2 = cip[2];
                    ci[0]=c0.x; ci[1]=c0.y; ci[2]=c0.z; ci[3]=c0.w;
                    ci[4]=c1.x; ci[5]=c1.y; ci[6]=c1.z; ci[7]=c1.w;
                    ci[8]=c2.x;
                }
                float px = PX[t], py = PY[t], pz = PZ[t];
                float ax = AX[t], ay = AY[t], az = AZ[t];

                float f0 = fmaf(px, ci[0], fmaf(py, ci[3], pz*ci[6]));
                float f1 = fmaf(px, ci[1], fmaf(py, ci[4], pz*ci[7]));
                float f2 = fmaf(px, ci[2], fmaf(py, ci[5], pz*ci[8]));
                float t0 = f0 - floorf(f0) - 0.5f;
                float t1 = f1 - floorf(f1) - 0.5f;
                float t2 = f2 - floorf(f2) - 0.5f;

                h2[t][0].x = h2[t][0].y = ax;
                h2[t][1].x = h2[t][1].y = ay;
                h2[t][2].x = h2[t][2].y = az;
                #pragma unroll
                for (int r = 0; r < 3; r++) {
                    float4 a0 = q0[r], a1 = q1[r], a2 = q2[r];
                    float ap3 = leaky_(fmaf(ax, a0.x, fmaf(ay, a0.y, fmaf(az, a0.z, a0.w))));
                    float d1  = fmaf(t0, a1.x, fmaf(t1, a1.y, fmaf(t2, a1.z, a1.w)));
                    float d2  = a2.w - fmaf(t0, a2.x, fmaf(t1, a2.y, t2*a2.z));
                    float v1 = fmaxf(d1, 0.f) * ap3;
                    float v2 = fmaxf(d2, 0.f) * ap3;
                    h2[t][3+r].x = h2[t][3+r].y = v1;
                    h2[t][6+r].x = h2[t][6+r].y = v2;
                }
            }
        }

        // ---- phase 2: fused L1+relu+L2; b128 weight loads; cc pipelined ----
        v2f vv[CHUNK][8];
        {
            const v2f* b2b2 = (const v2f*)(lds + L_B2B);
            #pragma unroll
            for (int t = 0; t < CHUNK; t++)
                #pragma unroll
                for (int m2 = 0; m2 < 8; m2++) vv[t][m2] = b2b2[m2];
        }

        #pragma unroll
        for (int kb = 0; kb < 8; kb++) {
            float4 c4[CHUNK];
            #pragma unroll
            for (int t = 0; t < CHUNK; t++) c4[t] = c4n[t];
            if (kb < 7) {
                #pragma unroll
                for (int t = 0; t < CHUNK; t++) c4n[t] = *(const float4*)(ccp[t] + (kb+1)*4);
            }

            #pragma unroll
            for (int h = 0; h < 2; h++) {
                int kp = 2*kb + h;
                const float4* wI4  = (const float4*)(lds + L_W2AI + kp*20);
                float4 wq0 = wI4[0], wq1 = wI4[1], wq2 = wI4[2], wq3 = wI4[3], wq4 = wI4[4];
                v2f wj[9];
                wj[0].x=wq0.x; wj[0].y=wq0.y;  wj[1].x=wq0.z; wj[1].y=wq0.w;
                wj[2].x=wq1.x; wj[2].y=wq1.y;  wj[3].x=wq1.z; wj[3].y=wq1.w;
                wj[4].x=wq2.x; wj[4].y=wq2.y;  wj[5].x=wq2.z; wj[5].y=wq2.w;
                wj[6].x=wq3.x; wj[6].y=wq3.y;  wj[7].x=wq3.z; wj[7].y=wq3.w;
                wj[8].x=wq4.x; wj[8].y=wq4.y;

                const float4* wb04 = (const float4*)(lds + L_W2BT + (2*kp)*16);
                const float4* wb14 = (const float4*)(lds + L_W2BT + (2*kp+1)*16);
                float4 b0q[4], b1q[4];
                #pragma unroll
                for (int q = 0; q < 4; q++) { b0q[q] = wb04[q]; b1q[q] = wb14[q]; }
                v2f wb0v[8], wb1v[8];
                #pragma unroll
                for (int q = 0; q < 4; q++) {
                    wb0v[2*q].x   = b0q[q].x; wb0v[2*q].y   = b0q[q].y;
                    wb0v[2*q+1].x = b0q[q].z; wb0v[2*q+1].y = b0q[q].w;
                    wb1v[2*q].x   = b1q[q].x; wb1v[2*q].y   = b1q[q].y;
                    wb1v[2*q+1].x = b1q[q].z; wb1v[2*q+1].y = b1q[q].w;
                }

                #pragma unroll
                for (int t = 0; t < CHUNK; t++) {
                    v2f u2;
                    u2.x = h ? c4[t].z : c4[t].x;
                    u2.y = h ? c4[t].w : c4[t].y;
                    #pragma unroll
                    for (int j = 0; j < 9; j++) u2 = pk_fma(h2[t][j], wj[j], u2);
                    v2f zero = 0.f;
                    u2 = __builtin_elementwise_max(u2, zero);
                    v2f ux; ux.x = u2.x; ux.y = u2.x;
                    v2f uy; uy.x = u2.y; uy.y = u2.y;
                    #pragma unroll
                    for (int m2 = 0; m2 < 8; m2++) {
                        vv[t][m2] = pk_fma(ux, wb0v[m2], vv[t][m2]);
                        vv[t][m2] = pk_fma(uy, wb1v[m2], vv[t][m2]);
                    }
                }
            }
        }

        // ---- epilogue: leaky, L3 (16->6) ----
        {
            v2f zero = 0.f, small = 0.01f;
            #pragma unroll
            for (int t = 0; t < CHUNK; t++)
                #pragma unroll
                for (int m2 = 0; m2 < 8; m2++) {
                    v2f mx = __builtin_elementwise_max(vv[t][m2], zero);
                    v2f mn = __builtin_elementwise_min(vv[t][m2], zero);
                    vv[t][m2] = pk_fma(mn, small, mx);
                }
        }

        v2f oo[CHUNK][3];
        {
            const v2f* b2c2 = (const v2f*)(lds + L_B2C);
            #pragma unroll
            for (int t = 0; t < CHUNK; t++)
                #pragma unroll
                for (int p2 = 0; p2 < 3; p2++) oo[t][p2] = b2c2[p2];
        }
        #pragma unroll
        for (int m2 = 0; m2 < 8; m2++) {
            const float4* wc04 = (const float4*)(lds + L_W2CT + (2*m2)*8);
            const float4* wc14 = (const float4*)(lds + L_W2CT + (2*m2+1)*8);
            float4 c0q0 = wc04[0], c0q1 = wc04[1];
            float4 c1q0 = wc14[0], c1q1 = wc14[1];
            v2f wc0v[3], wc1v[3];
            wc0v[0].x=c0q0.x; wc0v[0].y=c0q0.y; wc0v[1].x=c0q0.z; wc0v[1].y=c0q0.w;
            wc0v[2].x=c0q1.x; wc0v[2].y=c0q1.y;
            wc1v[0].x=c1q0.x; wc1v[0].y=c1q0.y; wc1v[1].x=c1q0.z; wc1v[1].y=c1q0.w;
            wc1v[2].x=c1q1.x; wc1v[2].y=c1q1.y;
            #pragma unroll
            for (int t = 0; t < CHUNK; t++) {
                v2f vm = vv[t][m2];
                v2f a; a.x = vm.x; a.y = vm.x;
                v2f b; b.x = vm.y; b.y = vm.y;
                #pragma unroll
                for (int p2 = 0; p2 < 3; p2++)
                    oo[t][p2] = pk_fma(a, wc0v[p2], pk_fma(b, wc1v[p2], oo[t][p2]));
            }
        }

        // ---- per-lane final (key, value) ----
        const int SENT = INT_MAX;
        int fs;
        float fin[6];
        {
            int sA = sv[0], sB = sv[1];
            if (sA < 0) {
                fs = SENT;
                #pragma unroll
                for (int p = 0; p < 6; p++) fin[p] = 0.f;
            } else if (sB == sA) {
                fs = sA;
                fin[0] = oo[0][0].x + oo[1][0].x; fin[1] = oo[0][0].y + oo[1][0].y;
                fin[2] = oo[0][1].x + oo[1][1].x; fin[3] = oo[0][1].y + oo[1][1].y;
                fin[4] = oo[0][2].x + oo[1][2].x; fin[5] = oo[0][2].y + oo[1][2].y;
            } else {
                float v0[6] = {oo[0][0].x, oo[0][0].y, oo[0][1].x, oo[0][1].y, oo[0][2].x, oo[0][2].y};
                int idx = sA - s0;
                if (idx >= 0 && idx < SPAN) {
                    #pragma unroll
                    for (int p = 0; p < 6; p++) atomicAdd(&lds[L_ACC + idx*6 + p], v0[p]);
                } else {
                    #pragma unroll
                    for (int p = 0; p < 6; p++) atomicAdd(out + (size_t)sA*6 + p, v0[p]);
                }
                if (sB >= 0) {
                    fs = sB;
                    fin[0] = oo[1][0].x; fin[1] = oo[1][0].y;
                    fin[2] = oo[1][1].x; fin[3] = oo[1][1].y;
                    fin[4] = oo[1][2].x; fin[5] = oo[1][2].y;
                } else {
                    fs = SENT;
                    #pragma unroll
                    for (int p = 0; p < 6; p++) fin[p] = 0.f;
                }
            }
        }

        // ---- segmented inclusive scan across the wave (keys sorted) ----
        int lane = tid & 63;
        #pragma unroll
        for (int d = 1; d < 64; d <<= 1) {
            int ks = __shfl_up(fs, d);
            bool pred = (lane >= d) && (ks == fs);
            #pragma unroll
            for (int p = 0; p < 6; p++) {
                float vp = __shfl_up(fin[p], d);
                fin[p] += pred ? vp : 0.f;
            }
        }
        {
            int sn = __shfl_down(fs, 1);
            bool tail = (lane == 63) || (sn != fs);
            if (tail && fs != SENT) {
                int idx = fs - s0;
                if (idx >= 0 && idx < SPAN) {
                    #pragma unroll
                    for (int p = 0; p < 6; p++) atomicAdd(&lds[L_ACC + idx*6 + p], fin[p]);
                } else {
                    #pragma unroll
                    for (int p = 0; p < 6; p++) atomicAdd(out + (size_t)fs*6 + p, fin[p]);
                }
            }
        }

        __syncthreads();

        // cooperative flush of LDS accumulator to global (skip untouched slots)
        for (int e = tid; e < SPAN*6; e += BLOCK) {
            int idx = e / 6, p = e - idx*6;
            int sg = s0 + idx;
            float v = lds[L_ACC + e];
            if (sg < S && v != 0.f) atomicAdd(out + (size_t)sg*6 + p, v);
        }
    }
}

extern "C" void kernel_launch(void* const* d_in, const int* in_sizes, int n_in,
                              void* d_out, int out_size, void* d_ws, size_t ws_size,
                              hipStream_t stream)
{
    const float* atom_prop = (const float*)d_in[0];
    const float* pos       = (const float*)d_in[1];
    const float* cell      = (const float*)d_in[2];
    const int*   batch     = (const int*)  d_in[3];
    const float* w0  = (const float*)d_in[4];
    const float* b0  = (const float*)d_in[5];
    const float* w1  = (const float*)d_in[6];
    const float* b1  = (const float*)d_in[7];
    const float* w1n = (const float*)d_in[8];
    const float* b1n = (const float*)d_in[9];
    const float* w2a = (const float*)d_in[10];
    const float* b2a = (const float*)d_in[11];
    const float* w2b = (const float*)d_in[12];
    const float* b2b = (const float*)d_in[13];
    const float* w2c = (const float*)d_in[14];
    const float* b2c = (const float*)d_in[15];

    int N = in_sizes[3];          // batch has one entry per atom
    int S = in_sizes[2] / 9;      // cell is [S,3,3]

    float* out   = (float*)d_out;
    float* ci_ws = (float*)d_ws;                 // [S*12]
    float* cc_ws = ci_ws + (size_t)S*12;         // [S*32]
    float* wtab  = cc_ws + (size_t)S*32;         // [1024]

    int prep_threads = S * 32;
    prep_kernel<<<(prep_threads + 255)/256, 256, 0, stream>>>(
        cell, w2a, b2a, w2b, w2c, w0, b0, w1, b1, w1n, b1n, b2b, b2c,
        ci_ws, cc_ws, wtab, out, S);

    int tile_atoms = BLOCK * CHUNK;
    int ntiles = (N + tile_atoms - 1) / tile_atoms;
    int grid = ntiles < PERSIST_BLOCKS ? ntiles : PERSIST_BLOCKS;
    main_kernel<<<grid, BLOCK, 0, stream>>>(atom_prop, pos, batch,
                                            ci_ws, cc_ws, wtab, out, N, S, ntiles);
}

// Round 11
// 172.119 us; speedup vs baseline: 3.0114x; 3.0114x over previous
//
#include <hip/hip_runtime.h>
#include <limits.h>

#define BLOCK 256
#define CHUNK 2
#define SPAN  64
#define PERSIST_BLOCKS 2048   // 8 blocks/CU x 256 CUs; NO min-waves launch bound!

typedef float v2f __attribute__((ext_vector_type(2)));

__device__ __forceinline__ v2f pk_fma(v2f a, v2f b, v2f c) {
    return __builtin_elementwise_fma(a, b, c);
}
__device__ __forceinline__ float leaky_(float x){ return x >= 0.f ? x : 0.01f*x; }

// Packed weight-table layout (floats), built once by prep, block-copied to LDS:
#define L_W2AI   0      // 16*20: k-pair interleaved L1 weights {w2a[2kp][j],w2a[2kp+1][j]} j<9, pad 2
#define L_W2BT   320    // 32*16: w2bT[k][m] = w2b[m*32+k]
#define L_W2CT   832    // 16*8 : w2cT[m][p] = w2c[p*16+m], pad p<8
#define L_B2B    960    // 16
#define L_B2C    976    // 8 (pad)
#define L_W013   984    // 3 mats x 3 rows x4: (w,w,w,b) for w0,w1,w1n
#define WTAB_SZ  1024
#define L_ACC    1024   // SPAN*6 block-local segment accumulator
#define L_TOT    (1024 + SPAN*6)

// ---------------- Kernel A: per-structure precompute + weight packing ------
// w2a is staged into LDS with coalesced float4 loads; the 81-term cell
// contraction then reads LDS (stride-90 per lane = 2-way bank alias = free)
// instead of issuing 81 scattered global loads per thread (~42M total, ~90 us).
__global__ void prep_kernel(const float* __restrict__ cell,
                            const float* __restrict__ w2a,
                            const float* __restrict__ b2a,
                            const float* __restrict__ w2b,
                            const float* __restrict__ w2c,
                            const float* __restrict__ w0, const float* __restrict__ b0,
                            const float* __restrict__ w1, const float* __restrict__ b1,
                            const float* __restrict__ w1n, const float* __restrict__ b1n,
                            const float* __restrict__ b2b, const float* __restrict__ b2c,
                            float* __restrict__ ci_out,
                            float* __restrict__ cc_out,
                            float* __restrict__ wtab,
                            float* __restrict__ out_zero,
                            int S)
{
    __shared__ float sw[2880];          // all of w2a [32][90]
    int tid = threadIdx.x;
    int gid = blockIdx.x * blockDim.x + tid;

    #pragma unroll
    for (int t = 0; t < 3; t++) {
        int idx = tid + t*256;
        if (idx < 720) ((float4*)sw)[idx] = ((const float4*)w2a)[idx];
    }

    if (gid < S * 6) out_zero[gid] = 0.f;

    // ---- wtab packing (few threads; scattered loads negligible) ----
    if (gid < 320) {
        int kp = gid / 20, idx = gid % 20;
        int j = idx >> 1, h = idx & 1;
        wtab[L_W2AI + gid] = (idx < 18) ? w2a[(2*kp + h)*90 + j] : 0.f;
    } else if (gid < 832) {
        int t = gid - 320; int k = t >> 4, m = t & 15;
        wtab[gid] = w2b[m*32 + k];
    } else if (gid < 960) {
        int t = gid - 832; int m = t >> 3, p = t & 7;
        wtab[gid] = (p < 6) ? w2c[p*16 + m] : 0.f;
    } else if (gid < 976) {
        wtab[gid] = b2b[gid - 960];
    } else if (gid < 984) {
        int t = gid - 976; wtab[gid] = (t < 6) ? b2c[t] : 0.f;
    } else if (gid < 1024) {
        int t = gid - 984;
        if (t < 36) {
            int mat = t / 12, rr = t % 12, r = rr >> 2, c = rr & 3;
            const float* W = (mat == 0) ? w0 : (mat == 1) ? w1 : w1n;
            const float* B = (mat == 0) ? b0 : (mat == 1) ? b1 : b1n;
            wtab[gid] = (c < 3) ? W[r*3 + c] : B[r];
        } else wtab[gid] = 0.f;
    }

    __syncthreads();

    int s = gid >> 5;
    if (s >= S) return;
    int k = gid & 31;

    float cr[9];
    #pragma unroll
    for (int j = 0; j < 9; j++) cr[j] = cell[s*9 + j];

    if (k == 0) {
        float a=cr[0],b=cr[1],c=cr[2],d=cr[3],e=cr[4],f=cr[5],g=cr[6],h=cr[7],i=cr[8];
        float A = e*i - f*h;
        float B = f*g - d*i;
        float C = d*h - e*g;
        float det = a*A + b*B + c*C;
        float r = 1.0f / det;
        float* o = ci_out + s*12;
        o[0] = A*r;         o[1] = (c*h - b*i)*r; o[2] = (b*f - c*e)*r;
        o[3] = B*r;         o[4] = (a*i - c*g)*r; o[5] = (c*d - a*f)*r;
        o[6] = C*r;         o[7] = (b*g - a*h)*r; o[8] = (a*e - b*d)*r;
        o[9] = 0.f; o[10] = 0.f; o[11] = 0.f;
    }

    float acc = b2a[k];
    const float* wr = sw + k*90 + 9;     // LDS now
    #pragma unroll
    for (int j1 = 0; j1 < 9; j1++) {
        float c1 = cr[j1];
        #pragma unroll
        for (int j2 = 0; j2 < 9; j2++)
            acc = fmaf(c1 * cr[j2], wr[j1*9 + j2], acc);
    }
    cc_out[s*32 + k] = acc;
}

// ---------------- Kernel B: persistent per-atom MLP + segment sum ----------
// Body identical to the proven 65us R8 kernel; only wrapped in a tile loop.
// NO min-waves launch bound (the allocator spills under a VGPR cap).
__global__ __launch_bounds__(BLOCK)
void main_kernel(const float* __restrict__ atom_prop,
                 const float* __restrict__ pos,
                 const int*   __restrict__ batch,
                 const float* __restrict__ ci_ws,
                 const float* __restrict__ cc_ws,
                 const float* __restrict__ wtab,
                 float* __restrict__ out,
                 int N, int S, int ntiles)
{
    __shared__ float lds[L_TOT];
    int tid = threadIdx.x;

    // one coalesced float4 per thread loads the whole weight table
    ((float4*)lds)[tid] = ((const float4*)wtab)[tid];

    for (int tile = blockIdx.x; tile < ntiles; tile += gridDim.x) {
        long long blk_base = (long long)tile * (BLOCK * CHUNK);
        int s0 = batch[(blk_base < N) ? blk_base : (N - 1)];

        for (int t = tid; t < SPAN*6; t += BLOCK) lds[L_ACC + t] = 0.f;
        __syncthreads();

        long long base = blk_base + (long long)tid * CHUNK;
        bool any = (base < N);

        int   sv[CHUNK];
        float PX[CHUNK], PY[CHUNK], PZ[CHUNK];
        float AX[CHUNK], AY[CHUNK], AZ[CHUNK];

        if (any && base + CHUNK <= N) {
            int2 bb = *(const int2*)(batch + base);
            sv[0] = bb.x; sv[1] = bb.y;
            const float2* pp = (const float2*)(pos + 3*base);
            float2 p0 = pp[0], p1 = pp[1], p2 = pp[2];
            PX[0]=p0.x; PY[0]=p0.y; PZ[0]=p1.x;
            PX[1]=p1.y; PY[1]=p2.x; PZ[1]=p2.y;
            const float2* ap = (const float2*)(atom_prop + 3*base);
            float2 a0 = ap[0], a1 = ap[1], a2 = ap[2];
            AX[0]=a0.x; AY[0]=a0.y; AZ[0]=a1.x;
            AX[1]=a1.y; AY[1]=a2.x; AZ[1]=a2.y;
        } else {
            #pragma unroll
            for (int t = 0; t < CHUNK; t++) {
                long long i = base + t;
                bool ok = any && (i < N);
                sv[t] = ok ? batch[i] : -1;
                PX[t] = ok ? pos[3*i]   : 0.f;
                PY[t] = ok ? pos[3*i+1] : 0.f;
                PZ[t] = ok ? pos[3*i+2] : 0.f;
                AX[t] = ok ? atom_prop[3*i]   : 0.f;
                AY[t] = ok ? atom_prop[3*i+1] : 0.f;
                AZ[t] = ok ? atom_prop[3*i+2] : 0.f;
            }
        }

        // issue cc prefetch early (independent of phase 1)
        const float* ccp[CHUNK];
        #pragma unroll
        for (int t = 0; t < CHUNK; t++) {
            int s = sv[t] < 0 ? 0 : sv[t];
            ccp[t] = cc_ws + (size_t)s*32;
        }
        float4 c4n[CHUNK];
        #pragma unroll
        for (int t = 0; t < CHUNK; t++) c4n[t] = *(const float4*)(ccp[t]);

        // ---- phase 1: h per atom (splat pairs) ----
        v2f h2[CHUNK][9];
        {
            const float4* q0 = (const float4*)(lds + L_W013);
            const float4* q1 = (const float4*)(lds + L_W013 + 12);
            const float4* q2 = (const float4*)(lds + L_W013 + 24);
            int   cur_s = -1;
            float ci[9];
            #pragma unroll
            for (int t = 0; t < CHUNK; t++) {
                int s = sv[t];
                if (s < 0) {
                    #pragma unroll
                    for (int j = 0; j < 9; j++) h2[t][j] = 0.f;
                    continue;
                }
                if (s != cur_s) {
                    cur_s = s;
                    const float4* cip = (const float4*)(ci_ws + (size_t)s*12);
                    float4 c0 = cip[0], c1 = cip[1], c2 = cip[2];
                    ci[0]=c0.x; ci[1]=c0.y; ci[2]=c0.z; ci[3]=c0.w;
                    ci[4]=c1.x; ci[5]=c1.y; ci[6]=c1.z; ci[7]=c1.w;
                    ci[8]=c2.x;
                }
                float px = PX[t], py = PY[t], pz = PZ[t];
                float ax = AX[t], ay = AY[t], az = AZ[t];

                float f0 = fmaf(px, ci[0], fmaf(py, ci[3], pz*ci[6]));
                float f1 = fmaf(px, ci[1], fmaf(py, ci[4], pz*ci[7]));
                float f2 = fmaf(px, ci[2], fmaf(py, ci[5], pz*ci[8]));
                float t0 = f0 - floorf(f0) - 0.5f;
                float t1 = f1 - floorf(f1) - 0.5f;
                float t2 = f2 - floorf(f2) - 0.5f;

                h2[t][0].x = h2[t][0].y = ax;
                h2[t][1].x = h2[t][1].y = ay;
                h2[t][2].x = h2[t][2].y = az;
                #pragma unroll
                for (int r = 0; r < 3; r++) {
                    float4 a0 = q0[r], a1 = q1[r], a2 = q2[r];
                    float ap3 = leaky_(fmaf(ax, a0.x, fmaf(ay, a0.y, fmaf(az, a0.z, a0.w))));
                    float d1  = fmaf(t0, a1.x, fmaf(t1, a1.y, fmaf(t2, a1.z, a1.w)));
                    float d2  = a2.w - fmaf(t0, a2.x, fmaf(t1, a2.y, t2*a2.z));
                    float v1 = fmaxf(d1, 0.f) * ap3;
                    float v2 = fmaxf(d2, 0.f) * ap3;
                    h2[t][3+r].x = h2[t][3+r].y = v1;
                    h2[t][6+r].x = h2[t][6+r].y = v2;
                }
            }
        }

        // ---- phase 2: fused L1+relu+L2; k-pair packed; LDS weights;
        //      cc loads software-pipelined 1 block deep ----
        v2f vv[CHUNK][8];
        {
            const v2f* b2b2 = (const v2f*)(lds + L_B2B);
            #pragma unroll
            for (int t = 0; t < CHUNK; t++)
                #pragma unroll
                for (int m2 = 0; m2 < 8; m2++) vv[t][m2] = b2b2[m2];
        }

        #pragma unroll
        for (int kb = 0; kb < 8; kb++) {
            float4 c4[CHUNK];
            #pragma unroll
            for (int t = 0; t < CHUNK; t++) c4[t] = c4n[t];
            if (kb < 7) {
                #pragma unroll
                for (int t = 0; t < CHUNK; t++) c4n[t] = *(const float4*)(ccp[t] + (kb+1)*4);
            }

            #pragma unroll
            for (int h = 0; h < 2; h++) {
                int kp = 2*kb + h;
                const v2f* wI  = (const v2f*)(lds + L_W2AI + kp*20);       // uniform -> broadcast
                const v2f* wb0 = (const v2f*)(lds + L_W2BT + (2*kp)*16);
                const v2f* wb1 = (const v2f*)(lds + L_W2BT + (2*kp+1)*16);
                #pragma unroll
                for (int t = 0; t < CHUNK; t++) {
                    v2f u2;
                    u2.x = h ? c4[t].z : c4[t].x;
                    u2.y = h ? c4[t].w : c4[t].y;
                    #pragma unroll
                    for (int j = 0; j < 9; j++) u2 = pk_fma(h2[t][j], wI[j], u2);
                    v2f zero = 0.f;
                    u2 = __builtin_elementwise_max(u2, zero);
                    v2f ux; ux.x = u2.x; ux.y = u2.x;
                    v2f uy; uy.x = u2.y; uy.y = u2.y;
                    #pragma unroll
                    for (int m2 = 0; m2 < 8; m2++) {
                        vv[t][m2] = pk_fma(ux, wb0[m2], vv[t][m2]);
                        vv[t][m2] = pk_fma(uy, wb1[m2], vv[t][m2]);
                    }
                }
            }
        }

        // ---- epilogue: leaky, L3 (16->6) ----
        {
            v2f zero = 0.f, small = 0.01f;
            #pragma unroll
            for (int t = 0; t < CHUNK; t++)
                #pragma unroll
                for (int m2 = 0; m2 < 8; m2++) {
                    v2f mx = __builtin_elementwise_max(vv[t][m2], zero);
                    v2f mn = __builtin_elementwise_min(vv[t][m2], zero);
                    vv[t][m2] = pk_fma(mn, small, mx);
                }
        }

        v2f oo[CHUNK][3];
        {
            const v2f* b2c2 = (const v2f*)(lds + L_B2C);
            #pragma unroll
            for (int t = 0; t < CHUNK; t++)
                #pragma unroll
                for (int p2 = 0; p2 < 3; p2++) oo[t][p2] = b2c2[p2];
        }
        #pragma unroll
        for (int m2 = 0; m2 < 8; m2++) {
            const v2f* wc0 = (const v2f*)(lds + L_W2CT + (2*m2)*8);   // uniform
            const v2f* wc1 = (const v2f*)(lds + L_W2CT + (2*m2+1)*8);
            #pragma unroll
            for (int t = 0; t < CHUNK; t++) {
                v2f vm = vv[t][m2];
                v2f a; a.x = vm.x; a.y = vm.x;
                v2f b; b.x = vm.y; b.y = vm.y;
                #pragma unroll
                for (int p2 = 0; p2 < 3; p2++)
                    oo[t][p2] = pk_fma(a, wc0[p2], pk_fma(b, wc1[p2], oo[t][p2]));
            }
        }

        // ---- per-lane final (key, value) ----
        const int SENT = INT_MAX;
        int fs;
        float fin[6];
        {
            int sA = sv[0], sB = sv[1];
            if (sA < 0) {
                fs = SENT;
                #pragma unroll
                for (int p = 0; p < 6; p++) fin[p] = 0.f;
            } else if (sB == sA) {
                fs = sA;
                fin[0] = oo[0][0].x + oo[1][0].x; fin[1] = oo[0][0].y + oo[1][0].y;
                fin[2] = oo[0][1].x + oo[1][1].x; fin[3] = oo[0][1].y + oo[1][1].y;
                fin[4] = oo[0][2].x + oo[1][2].x; fin[5] = oo[0][2].y + oo[1][2].y;
            } else {
                float v0[6] = {oo[0][0].x, oo[0][0].y, oo[0][1].x, oo[0][1].y, oo[0][2].x, oo[0][2].y};
                int idx = sA - s0;
                if (idx >= 0 && idx < SPAN) {
                    #pragma unroll
                    for (int p = 0; p < 6; p++) atomicAdd(&lds[L_ACC + idx*6 + p], v0[p]);
                } else {
                    #pragma unroll
                    for (int p = 0; p < 6; p++) atomicAdd(out + (size_t)sA*6 + p, v0[p]);
                }
                if (sB >= 0) {
                    fs = sB;
                    fin[0] = oo[1][0].x; fin[1] = oo[1][0].y;
                    fin[2] = oo[1][1].x; fin[3] = oo[1][1].y;
                    fin[4] = oo[1][2].x; fin[5] = oo[1][2].y;
                } else {
                    fs = SENT;
                    #pragma unroll
                    for (int p = 0; p < 6; p++) fin[p] = 0.f;
                }
            }
        }

        // ---- segmented inclusive scan across the wave (keys sorted) ----
        int lane = tid & 63;
        #pragma unroll
        for (int d = 1; d < 64; d <<= 1) {
            int ks = __shfl_up(fs, d);
            bool pred = (lane >= d) && (ks == fs);
            #pragma unroll
            for (int p = 0; p < 6; p++) {
                float vp = __shfl_up(fin[p], d);
                fin[p] += pred ? vp : 0.f;
            }
        }
        {
            int sn = __shfl_down(fs, 1);
            bool tail = (lane == 63) || (sn != fs);
            if (tail && fs != SENT) {
                int idx = fs - s0;
                if (idx >= 0 && idx < SPAN) {
                    #pragma unroll
                    for (int p = 0; p < 6; p++) atomicAdd(&lds[L_ACC + idx*6 + p], fin[p]);
                } else {
                    #pragma unroll
                    for (int p = 0; p < 6; p++) atomicAdd(out + (size_t)fs*6 + p, fin[p]);
                }
            }
        }

        __syncthreads();

        // cooperative flush of LDS accumulator to global (skip untouched slots)
        for (int e = tid; e < SPAN*6; e += BLOCK) {
            int idx = e / 6, p = e - idx*6;
            int sg = s0 + idx;
            float v = lds[L_ACC + e];
            if (sg < S && v != 0.f) atomicAdd(out + (size_t)sg*6 + p, v);
        }

        __syncthreads();   // flush reads done before next tile's zeroing
    }
}

extern "C" void kernel_launch(void* const* d_in, const int* in_sizes, int n_in,
                              void* d_out, int out_size, void* d_ws, size_t ws_size,
                              hipStream_t stream)
{
    const float* atom_prop = (const float*)d_in[0];
    const float* pos       = (const float*)d_in[1];
    const float* cell      = (const float*)d_in[2];
    const int*   batch     = (const int*)  d_in[3];
    const float* w0  = (const float*)d_in[4];
    const float* b0  = (const float*)d_in[5];
    const float* w1  = (const float*)d_in[6];
    const float* b1  = (const float*)d_in[7];
    const float* w1n = (const float*)d_in[8];
    const float* b1n = (const float*)d_in[9];
    const float* w2a = (const float*)d_in[10];
    const float* b2a = (const float*)d_in[11];
    const float* w2b = (const float*)d_in[12];
    const float* b2b = (const float*)d_in[13];
    const float* w2c = (const float*)d_in[14];
    const float* b2c = (const float*)d_in[15];

    int N = in_sizes[3];          // batch has one entry per atom
    int S = in_sizes[2] / 9;      // cell is [S,3,3]

    float* out   = (float*)d_out;
    float* ci_ws = (float*)d_ws;                 // [S*12]
    float* cc_ws = ci_ws + (size_t)S*12;         // [S*32]
    float* wtab  = cc_ws + (size_t)S*32;         // [1024]

    int prep_threads = S * 32;
    prep_kernel<<<(prep_threads + 255)/256, 256, 0, stream>>>(
        cell, w2a, b2a, w2b, w2c, w0, b0, w1, b1, w1n, b1n, b2b, b2c,
        ci_ws, cc_ws, wtab, out, S);

    int tile_atoms = BLOCK * CHUNK;
    int ntiles = (N + tile_atoms - 1) / tile_atoms;
    int grid = ntiles < PERSIST_BLOCKS ? ntiles : PERSIST_BLOCKS;
    main_kernel<<<grid, BLOCK, 0, stream>>>(atom_prop, pos, batch,
                                            ci_ws, cc_ws, wtab, out, N, S, ntiles);
}